// Round 4
// baseline (468.191 us; speedup 1.0000x reference)
//
#include <hip/hip_runtime.h>
#include <hip/hip_bf16.h>

typedef __hip_bfloat16 bf16;
typedef short s16x8 __attribute__((ext_vector_type(8)));
typedef float f32x4 __attribute__((ext_vector_type(4)));
typedef unsigned int u32x4 __attribute__((ext_vector_type(4)));

#define DIM 2048
#define NHEADS 16
#define NKVH 4
#define HD 128
#define KVDIM 512
#define BSZ 4
#define SEQ 2048
#define MROWS (BSZ*SEQ)
#define NQKV (DIM+2*KVDIM)

// -------- async global->LDS, 16B per lane, wave-uniform LDS base --------
__device__ __forceinline__ void gld_lds16(const bf16* g, short* l) {
  __builtin_amdgcn_global_load_lds((__attribute__((address_space(1))) void*)(void*)g,
                                   (__attribute__((address_space(3))) void*)l, 16, 0, 0);
}

// -------- non-temporal (stream) stores: keep output streams out of L2 --------
__device__ __forceinline__ void nts16(void* p, uint4 v) {
  u32x4 w = {v.x, v.y, v.z, v.w};
  __builtin_nontemporal_store(w, (u32x4*)p);
}
__device__ __forceinline__ void nts8(void* p, unsigned long long v) {
  __builtin_nontemporal_store(v, (unsigned long long*)p);
}
__device__ __forceinline__ void nts16f(void* p, float4 v) {
  f32x4 w = {v.x, v.y, v.z, v.w};
  __builtin_nontemporal_store(w, (f32x4*)p);
}
__device__ __forceinline__ void nts2(void* p, bf16 v) {
  __builtin_nontemporal_store(*(short*)&v, (short*)p);
}

// -------- single fused fp32 -> bf16 cast for all five tensors --------
// groups of 8 elems: x 2097152 | Wq 524288 | Wk 131072 | Wv 131072 | Wo 524288
__global__ __launch_bounds__(256) void cast_all(
    const float* __restrict__ x,  const float* __restrict__ Wq,
    const float* __restrict__ Wk, const float* __restrict__ Wv,
    const float* __restrict__ Wo, bf16* __restrict__ xbf,
    bf16* __restrict__ Wqkv, bf16* __restrict__ Wob) {
  const int i = blockIdx.x*256 + threadIdx.x;      // 13312*256 = 3407872 exact
  const float* src; bf16* dst; int j, o;
  if (i < 2097152)      { src = x;  dst = xbf;  j = i;           o = i; }
  else if (i < 2621440) { src = Wq; dst = Wqkv; j = i - 2097152; o = i - 2097152; }
  else if (i < 2752512) { src = Wk; dst = Wqkv; j = i - 2621440; o = i - 2097152; }
  else if (i < 2883584) { src = Wv; dst = Wqkv; j = i - 2752512; o = i - 2097152; }
  else                  { src = Wo; dst = Wob;  j = i - 2883584; o = i - 2883584; }
  const float4* s4 = (const float4*)src;
  float4 a = s4[2*j];
  float4 b = s4[2*j+1];
  union { bf16 h[8]; uint4 u; } pk;
  pk.h[0] = __float2bfloat16(a.x); pk.h[1] = __float2bfloat16(a.y);
  pk.h[2] = __float2bfloat16(a.z); pk.h[3] = __float2bfloat16(a.w);
  pk.h[4] = __float2bfloat16(b.x); pk.h[5] = __float2bfloat16(b.y);
  pk.h[6] = __float2bfloat16(b.z); pk.h[7] = __float2bfloat16(b.w);
  nts16(((uint4*)dst) + o, pk.u);
}

// ==================== 256x256 / BK=64 / 8-wave / 8-phase GEMM ====================
// C[M,N] = A[M,K] @ B[N,K]^T, bf16 in, fp32 acc. K must be 2048 (32 K-tiles).
// T1: bijective XCD swizzle (both grids %8==0) - row-chunk per XCD L2.
// T2: st_16x32 LDS swizzle, inverse-permuted GLOBAL source + swizzled ds_read.
// T3+T4: 4 phases/K-tile, 1 half-tile staged per phase, single vmcnt(6)/K-tile.
// T5: s_setprio(1) around each 16-MFMA cluster.
// All output stores are NON-TEMPORAL: output streams must not evict the A/B
// K-slabs other co-resident blocks are reusing from this XCD's L2.
// EPI=1: V via packed 8B nt stores (s is register-contiguous in V^T layout);
//        Q/K with FUSED RMSNorm+RoPE+gain: transpose through 4 shared 32KB LDS
//        regions, barrier, per-row wave reduce + rope, nt store bf16.
// EPI=0: fp32 C via wave-private LDS transpose -> 128B coalesced nt rows.

template<int MQ>
__device__ __forceinline__ void lda(s16x8 (&af)[4][2], const short* pa, int rds) {
#pragma unroll
  for (int fr = 0; fr < 4; fr++)
#pragma unroll
    for (int ks = 0; ks < 2; ks++)
      af[fr][ks] = *(const s16x8*)(pa + ((MQ*4 + fr)*2 + ks)*512 + rds);
}
template<int NQ>
__device__ __forceinline__ void ldb(s16x8 (&bfv)[2][2], const short* pb, int bsub, int rds) {
#pragma unroll
  for (int fc = 0; fc < 2; fc++)
#pragma unroll
    for (int ks = 0; ks < 2; ks++)
      bfv[fc][ks] = *(const s16x8*)(pb + (bsub + (NQ*2 + fc)*2 + ks)*512 + rds);
}
template<int MQ, int NQ>
__device__ __forceinline__ void mmq(f32x4 (&acc)[8][4], const s16x8 (&af)[4][2],
                                    const s16x8 (&bfv)[2][2]) {
#pragma unroll
  for (int fr = 0; fr < 4; fr++)
#pragma unroll
    for (int fc = 0; fc < 2; fc++)
#pragma unroll
      for (int ks = 0; ks < 2; ks++)
        acc[MQ*4+fr][NQ*2+fc] = __builtin_amdgcn_mfma_f32_16x16x32_bf16(
            af[fr][ks], bfv[fc][ks], acc[MQ*4+fr][NQ*2+fc], 0, 0, 0);
}

#define WV6 asm volatile("s_waitcnt vmcnt(6)" ::: "memory")
#define WV0 asm volatile("s_waitcnt vmcnt(0)" ::: "memory")
#define WVN ((void)0)
#define GBAR __builtin_amdgcn_s_barrier()
#define WLK asm volatile("s_waitcnt lgkmcnt(0)" ::: "memory")
#define PRI1 __builtin_amdgcn_s_setprio(1)
#define PRI0 __builtin_amdgcn_s_setprio(0)

#define KT(B_, T_, S1_, S2_, WVX) do {                                          \
    const short* pa = pAr[B_];                                                  \
    const short* pb = pBr[B_];                                                  \
    s16x8 af[4][2], b0f[2][2], b1f[2][2];                                       \
    /* phase 1: quad(0,0) */                                                    \
    lda<0>(af, pa, rds); ldb<0>(b0f, pb, bsub, rds);                            \
    if (S1_) {                                                                  \
      gld_lds16(Ab +      (long)((T_)+1)*64 + eA1, &L[1-(B_)][0][4096+wid512]); \
      gld_lds16(Ab + h1 + (long)((T_)+1)*64 + eA1, &L[1-(B_)][1][4096+wid512]); \
    }                                                                           \
    GBAR; WLK; PRI1; mmq<0,0>(acc, af, b0f); PRI0; GBAR;                        \
    /* phase 2: quad(0,1) */                                                    \
    ldb<1>(b1f, pb, bsub, rds);                                                 \
    if (S2_) {                                                                  \
      gld_lds16(Ab +      (long)((T_)+2)*64 + eA0, &L[B_][0][wid512]);          \
      gld_lds16(Ab + h1 + (long)((T_)+2)*64 + eA0, &L[B_][1][wid512]);          \
    }                                                                           \
    GBAR; WLK; PRI1; mmq<0,1>(acc, af, b1f); PRI0; GBAR;                        \
    /* phase 3: quad(1,0) */                                                    \
    lda<1>(af, pa, rds);                                                        \
    if (S2_) {                                                                  \
      gld_lds16(Bb + (long)((T_)+2)*64 + eA0, &L[B_][2][wid512]);               \
      gld_lds16(Bb + (long)((T_)+2)*64 + eA1, &L[B_][2][4096+wid512]);          \
    }                                                                           \
    GBAR; WLK; PRI1; mmq<1,0>(acc, af, b0f); PRI0; GBAR;                        \
    /* phase 4: quad(1,1) */                                                    \
    if (S2_) {                                                                  \
      gld_lds16(Bb + h1 + (long)((T_)+2)*64 + eA0, &L[B_][3][wid512]);          \
      gld_lds16(Bb + h1 + (long)((T_)+2)*64 + eA1, &L[B_][3][4096+wid512]);     \
    }                                                                           \
    WVX;                                                                        \
    GBAR; PRI1; mmq<1,1>(acc, af, b1f); PRI0; GBAR;                             \
  } while (0)

// EPI=0: plain fp32 C.  EPI=1: Q/K (fused norm+rope) / V^T[b,kvh,d,s].
template<int EPI>
__global__ __launch_bounds__(512, 2) void gemm8(
    const bf16* __restrict__ A, const bf16* __restrict__ Bm,
    float* __restrict__ Cf, bf16* __restrict__ Qo, bf16* __restrict__ Ko,
    bf16* __restrict__ Vo, const float* __restrict__ gain, int N, int K) {
  // [buf][slot: A-half0, A-half1, B-half0, B-half1][16KB as shorts]
  __shared__ short L[2][4][8192] __attribute__((aligned(16)));
  const int tid = threadIdx.x;
  const int lane = tid & 63, wid = tid >> 6;
  const int quad = lane >> 4, l15 = lane & 15;
  const int wm = wid >> 2, wn = wid & 3;          // 2 M-waves x 4 N-waves

  // ---- T1: bijective XCD swizzle (nwg % 8 == 0 for both grids) ----
  const int gx  = gridDim.x;
  const int lin = blockIdx.y * gx + blockIdx.x;
  const int cpx = (gx * gridDim.y) >> 3;
  const int swz = (lin & 7) * cpx + (lin >> 3);
  const int m0 = (swz / gx) * 256, n0 = (swz % gx) * 256;

  // ---- swizzled ds_read lane offset (shorts within a half-tile slot) ----
  const int rds = l15*32 + ((quad*8) ^ ((l15 & 8) << 1));
  const int bsub = (wn & 1) * 8;                  // B strip within its half: 8 subtiles

  // ---- staging source offsets (inverse-swizzled global address, linear LDS dest) ----
  const int colx = ((lane & 3) * 8) ^ ((lane >> 5) << 4);
  const int gc   = ((wid & 1) << 5) + colx;
  const int gr0  = ((wid >> 1) << 4) + (lane >> 2);
  const long eA0 = (long)gr0 * K + gc;            // j=0 chunk: rows 0-63 of half
  const long eA1 = eA0 + 64L * K;                 // j=1 chunk: rows 64-127
  const int wid512 = wid * 512;
  const bf16* Ab = A  + (long)m0 * K;
  const bf16* Bb = Bm + (long)n0 * K;
  const long h1 = 128L * K;                       // half-1 row offset

  const short* pAr[2] = { &L[0][wm][0], &L[1][wm][0] };
  const short* pBr[2] = { &L[0][2 + (wn >> 1)][0], &L[1][2 + (wn >> 1)][0] };

  f32x4 acc[8][4] = {};

  // ---- prologue: K0 complete (8 chunks) + K1 partial (A-L0s, B: 6 chunks) ----
  gld_lds16(Ab + eA0,           &L[0][0][wid512]);
  gld_lds16(Ab + eA1,           &L[0][0][4096 + wid512]);
  gld_lds16(Ab + h1 + eA0,      &L[0][1][wid512]);
  gld_lds16(Ab + h1 + eA1,      &L[0][1][4096 + wid512]);
  gld_lds16(Bb + eA0,           &L[0][2][wid512]);
  gld_lds16(Bb + eA1,           &L[0][2][4096 + wid512]);
  gld_lds16(Bb + h1 + eA0,      &L[0][3][wid512]);
  gld_lds16(Bb + h1 + eA1,      &L[0][3][4096 + wid512]);
  gld_lds16(Ab + 64 + eA0,      &L[1][0][wid512]);
  gld_lds16(Ab + h1 + 64 + eA0, &L[1][1][wid512]);
  gld_lds16(Bb + 64 + eA0,      &L[1][2][wid512]);
  gld_lds16(Bb + 64 + eA1,      &L[1][2][4096 + wid512]);
  gld_lds16(Bb + h1 + 64 + eA0, &L[1][3][wid512]);
  gld_lds16(Bb + h1 + 64 + eA1, &L[1][3][4096 + wid512]);
  WV6;   // K0's 8 landed; K1's 6 in flight
  GBAR;

  // ---- main loop: 32 K-tiles (K=2048), steady pairs then drained tail ----
  for (int t = 0; t < 30; t += 2) {
    KT(0, t,   1, 1, WV6);
    KT(1, t+1, 1, 1, WV6);
  }
  KT(0, 30, 1, 0, WV0);   // WV0 also drains tile-31 staging -> LDS reusable below
  KT(1, 31, 0, 0, WVN);

  // ---- epilogue ----
  const int colg0 = n0 + wn*64;                   // wave's first output column
  const int bb = (m0 + wm*128) >> 11;             // batch (tile never crosses)
  const int sb = (m0 + wm*128) & (SEQ-1);         // seq base of wave's 128 rows
  if (EPI == 0) {
    // fp32 C via wave-private LDS transpose, two 32-col halves -> 128B nt rows
    float* ew = (float*)(&L[0][0][0]) + wid*4096; // 16KB slice: [128 rows][32 cols]
    const int rowb = m0 + wm*128;
    const int rr = lane >> 3, c4 = (lane & 7)*4;
#pragma unroll
    for (int half = 0; half < 2; half++) {
#pragma unroll
      for (int mi = 0; mi < 8; mi++)
#pragma unroll
        for (int nj2 = 0; nj2 < 2; nj2++)
#pragma unroll
          for (int r = 0; r < 4; r++)
            ew[(mi*16 + quad*4 + r)*32 + nj2*16 + l15] = acc[mi][half*2 + nj2][r];
      asm volatile("" ::: "memory");              // pin write->read order (in-wave)
#pragma unroll
      for (int it = 0; it < 16; it++) {
        const int row = it*8 + rr;
        float4 v = *(const float4*)&ew[row*32 + c4];
        nts16f(Cf + (long)(rowb + row)*N + colg0 + half*32 + c4, v);
      }
      asm volatile("" ::: "memory");              // pin read->next-half-write order
    }
  } else if (n0 >= DIM + KVDIM) {
    // V block: 4 s-contiguous rows per acc quad -> one 8B nt store each
    const int cv = colg0 - (DIM + KVDIM);
    const int h  = cv >> 7;                       // wave-uniform
    const int db = cv & 127;
    bf16* vb = Vo + ((long)(bb*NKVH + h)*HD)*SEQ + sb;
#pragma unroll
    for (int mi = 0; mi < 8; mi++)
#pragma unroll
      for (int nj = 0; nj < 4; nj++) {
        const int d = db + nj*16 + l15;
        union { bf16 h4[4]; unsigned long long u; } pk;
        pk.h4[0] = __float2bfloat16(acc[mi][nj][0]);
        pk.h4[1] = __float2bfloat16(acc[mi][nj][1]);
        pk.h4[2] = __float2bfloat16(acc[mi][nj][2]);
        pk.h4[3] = __float2bfloat16(acc[mi][nj][3]);
        nts8(vb + (long)d*SEQ + mi*16 + quad*4, pk.u);
      }
  } else {
    // Q/K block: FUSED RMSNorm + RoPE (+ q_gain*1/sqrt(HD)).
    // Transpose into shared region (wm, h2): [128 rows][128 head-cols] bf16 = 32KB,
    // 4 regions = full 128KB LDS. Wave pair (wn=2*h2, 2*h2+1) writes the two
    // 64-col halves; after barrier each wave norms 64 rows of its region.
    short* Ls = &L[0][0][0];
    short* rw = Ls + (wm*2 + (wn >> 1))*16384;
    const int cw = (wn & 1)*64;
#pragma unroll
    for (int mi = 0; mi < 8; mi++)
#pragma unroll
      for (int nj = 0; nj < 4; nj++)
#pragma unroll
        for (int r = 0; r < 4; r++) {
          bf16 hv = __float2bfloat16(acc[mi][nj][r]);
          rw[(mi*16 + quad*4 + r)*128 + cw + nj*16 + l15] = *(short*)&hv;
        }
    __syncthreads();
    const int h2 = wn >> 1;
    const short* rg = Ls + (wm*2 + h2)*16384;
    const int row0 = (wn & 1)*64;
    float g; bf16* gb;
    if (n0 < DIM) {
      const int h = (n0 >> 7) + h2;
      g = gain[h] * 0.08838834764831845f;   // fold softmax scale 1/sqrt(128) into q
      gb = Qo + (long)(bb*NHEADS + h)*SEQ*HD;
    } else {
      const int h = ((n0 - DIM) >> 7) + h2;
      g = 1.0f;
      gb = Ko + (long)(bb*NKVH + h)*SEQ*HD;
    }
    const float inv_freq = exp2f((float)lane * -0.20762050593046014f);
    for (int rI = 0; rI < 64; rI++) {
      const int row = row0 + rI;
      const float x1 = __bfloat162float(*(const bf16*)&rg[row*128 + lane]);
      const float x2 = __bfloat162float(*(const bf16*)&rg[row*128 + 64 + lane]);
      float ss = x1*x1 + x2*x2;
#pragma unroll
      for (int off = 1; off < 64; off <<= 1) ss += __shfl_xor(ss, off);
      const float rn = rsqrtf(ss*(1.0f/128.0f) + 1.1920928955078125e-07f);
      const int s = sb + row;
      float sn, cs;
      sincosf((float)s * inv_freq, &sn, &cs);
      const float q1 = x1*rn, q2 = x2*rn;
      bf16* pr = gb + (long)s*HD;
      nts2(pr + lane,      __float2bfloat16((q1*cs + q2*sn)*g));
      nts2(pr + 64 + lane, __float2bfloat16((q2*cs - q1*sn)*g));
    }
  }
}

// -------- causal flash attention: S^T form, fixed-shift softmax, qt-paired --------
// T14 async-STAGE split; T5 setprio; T1 XCD swizzle. Yb stores non-temporal
// (proj reads them next - keep them out of attn's L2s).
__global__ __launch_bounds__(256, 2) void attn(
    const bf16* __restrict__ Qb, const bf16* __restrict__ Kb,
    const bf16* __restrict__ Vtg, bf16* __restrict__ Yb) {
  __shared__ short Kt[64*136]  __attribute__((aligned(16)));  // [key][k] pad->136
  __shared__ short Vt[128*72]  __attribute__((aligned(16)));  // [d][key] pad->72
  __shared__ short Pt[4*2304]  __attribute__((aligned(16)));  // per-wave, per-group [16 q][72]

  const int tid = threadIdx.x;
  const int lane = tid & 63, wid = tid >> 6;
  const int quad = lane >> 4, l15 = lane & 15;
  const int lin = blockIdx.y*8 + blockIdx.x;    // 512 blocks, %8==0
  const int swz = (lin & 7)*64 + (lin >> 3);    // bijective XCD chunking
  const int xb = swz & 7;                       // 0..7
  const int bh = swz >> 3;
  const int b = bh >> 4, h = bh & 15, kvh = h >> 2;

  const bf16* kbase = Kb  + (long)(b*NKVH + kvh)*SEQ*HD;
  const bf16* vbase = Vtg + (long)(b*NKVH + kvh)*HD*SEQ;   // [d][s]
  short* pw0 = Pt + wid*2304;
  short* pw1 = pw0 + 1152;
  const int krow = tid >> 4, kc = (tid & 15)*8;
  const int vrow = tid >> 3, vc = (tid & 7)*8;

#define LOADK(KT_) do {                                                        \
    kr0 = *(const uint4*)(kbase + (long)((KT_)*64 +  0 + krow)*HD + kc);       \
    kr1 = *(const uint4*)(kbase + (long)((KT_)*64 + 16 + krow)*HD + kc);       \
    kr2 = *(const uint4*)(kbase + (long)((KT_)*64 + 32 + krow)*HD + kc);       \
    kr3 = *(const uint4*)(kbase + (long)((KT_)*64 + 48 + krow)*HD + kc);       \
  } while (0)
#define LOADV(KT_) do {                                                        \
    vr0 = *(const uint4*)(vbase + (long)(  0 + vrow)*SEQ + (KT_)*64 + vc);     \
    vr1 = *(const uint4*)(vbase + (long)( 32 + vrow)*SEQ + (KT_)*64 + vc);     \
    vr2 = *(const uint4*)(vbase + (long)( 64 + vrow)*SEQ + (KT_)*64 + vc);     \
    vr3 = *(const uint4*)(vbase + (long)( 96 + vrow)*SEQ + (KT_)*64 + vc);     \
  } while (0)

  for (int phase = 0; phase < 2; phase++) {
    const int qt = phase ? xb : (15 - xb);      // heavy first
    const int q0 = qt*128 + wid*16 + l15;       // group 0 query
    const int q1 = q0 + 64;                     // group 1 query
    const bf16* qr0 = Qb + ((long)(b*NHEADS + h)*SEQ + q0)*HD + quad*8;
    s16x8 qa0[4], qa1[4];
#pragma unroll
    for (int st = 0; st < 4; st++) {
      qa0[st] = *(const s16x8*)(qr0 + st*32);
      qa1[st] = *(const s16x8*)(qr0 + 64*HD + st*32);
    }

    f32x4 o0[8] = {}, o1[8] = {};
    float li0 = 0.0f, li1 = 0.0f;
    const int ktiles = 2*qt + 2;

    uint4 kr0, kr1, kr2, kr3, vr0, vr1, vr2, vr3;
    LOADK(0); LOADV(0);                          // prologue issue (exposed once)

    for (int kt = 0; kt < ktiles; kt++) {
      __syncthreads();                           // all waves done reading prev tile
      // publish tile kt (compiler inserts the vmcnt wait before first ds_write)
      *(uint4*)&Kt[( 0 + krow)*136 + kc] = kr0;
      *(uint4*)&Kt[(16 + krow)*136 + kc] = kr1;
      *(uint4*)&Kt[(32 + krow)*136 + kc] = kr2;
      *(uint4*)&Kt[(48 + krow)*136 + kc] = kr3;
      *(uint4*)&Vt[(  0 + vrow)*72 + vc] = vr0;
      *(uint4*)&Vt[( 32 + vrow)*72 + vc] = vr1;
      *(uint4*)&Vt[( 64 + vrow)*72 + vc] = vr2;
      *(uint4*)&Vt[( 96 + vrow)*72 + vc] = vr3;
      __syncthreads();                           // tile kt visible
      if (kt + 1 < ktiles) { LOADK(kt+1); LOADV(kt+1); }  // T14: hide under compute

      // S^T = K Q^T for both groups; kf frags shared
      f32x4 s0[4] = {}, s1[4] = {};
#pragma unroll
      for (int nt = 0; nt < 4; nt++) {
        s16x8 kf[4];
#pragma unroll
        for (int st = 0; st < 4; st++)
          kf[st] = *(const s16x8*)&Kt[(nt*16 + l15)*136 + st*32 + quad*8];
        PRI1;
#pragma unroll
        for (int st = 0; st < 4; st++) {
          s0[nt] = __builtin_amdgcn_mfma_f32_16x16x32_bf16(kf[st], qa0[st], s0[nt], 0, 0, 0);
          s1[nt] = __builtin_amdgcn_mfma_f32_16x16x32_bf16(kf[st], qa1[st], s1[nt], 0, 0, 0);
        }
        PRI0;
      }

      // fixed-shift softmax: P = exp(s - 12); |s|<11.5 provably (rms-normed q,k)
      const bool d0 = (kt >= 2*qt);
      const bool d1 = (kt >  2*qt);
      const int tb = kt*64 + quad*4;
      union { bf16 h[16]; unsigned long long u[4]; } p0, p1;
      float rs0 = 0.0f, rs1 = 0.0f;
#pragma unroll
      for (int nt = 0; nt < 4; nt++) {
#pragma unroll
        for (int r = 0; r < 4; r++) {
          const int t = tb + nt*16 + r;
          float v0 = s0[nt][r], v1 = s1[nt][r];
          if (d0 && (t > q0)) v0 = -1e30f;
          if (d1 && (t > q1)) v1 = -1e30f;
          const float e0 = __expf(v0 - 12.0f);
          const float e1 = __expf(v1 - 12.0f);
          rs0 += e0; rs1 += e1;
          p0.h[nt*4+r] = __float2bfloat16(e0);
          p1.h[nt*4+r] = __float2bfloat16(e1);
        }
      }
      li0 += rs0; li1 += rs1;
#pragma unroll
      for (int nt = 0; nt < 4; nt++) {
        *(unsigned long long*)&pw0[l15*72 + nt*16 + quad*4] = p0.u[nt];
        *(unsigned long long*)&pw1[l15*72 + nt*16 + quad*4] = p1.u[nt];
      }

      // O^T += V^T P^T for both groups; vf frags shared
#pragma unroll
      for (int st = 0; st < 2; st++) {
        s16x8 pf0 = *(const s16x8*)&pw0[l15*72 + st*32 + quad*8];
        s16x8 pf1 = *(const s16x8*)&pw1[l15*72 + st*32 + quad*8];
        PRI1;
#pragma unroll
        for (int dt = 0; dt < 8; dt++) {
          s16x8 vf = *(const s16x8*)&Vt[(dt*16 + l15)*72 + st*32 + quad*8];
          o0[dt] = __builtin_amdgcn_mfma_f32_16x16x32_bf16(vf, pf0, o0[dt], 0, 0, 0);
          o1[dt] = __builtin_amdgcn_mfma_f32_16x16x32_bf16(vf, pf1, o1[dt], 0, 0, 0);
        }
        PRI0;
      }
    }

    // finalize li (once per phase), then transpose O^T -> O via wave-private Pt slice
    li0 += __shfl_xor(li0, 16); li0 += __shfl_xor(li0, 32);
    li1 += __shfl_xor(li1, 16); li1 += __shfl_xor(li1, 32);
    const float inv0 = 1.0f / li0, inv1 = 1.0f / li1;

    short* ep = pw0;
#pragma unroll
    for (int g = 0; g < 2; g++) {
      const float inv = g ? inv1 : inv0;
      const f32x4* o = g ? o1 : o0;
      const int qg = g ? q1 : q0;
#pragma unroll
      for (int dt = 0; dt < 8; dt++) {
        union { bf16 h[4]; unsigned long long u; } pk;
        pk.h[0] = __float2bfloat16(o[dt][0]*inv);
        pk.h[1] = __float2bfloat16(o[dt][1]*inv);
        pk.h[2] = __float2bfloat16(o[dt][2]*inv);
        pk.h[3] = __float2bfloat16(o[dt][3]*inv);
        *(unsigned long long*)&ep[l15*136 + dt*16 + quad*4] = pk.u;
      }
      bf16* yb = Yb + ((long)(b*SEQ + qg - l15))*DIM + h*HD;
#pragma unroll
      for (int p = 0; p < 4; p++) {
        const int c = quad + 4*p;
        uint4 yv = *(const uint4*)&ep[l15*136 + c*8];
        nts16(&yb[(long)l15*DIM + c*8], yv);
      }
    }
  }
#undef LOADK
#undef LOADV
}

extern "C" void kernel_launch(void* const* d_in, const int* in_sizes, int n_in,
                              void* d_out, int out_size, void* d_ws, size_t ws_size,
                              hipStream_t stream) {
  (void)in_sizes; (void)n_in; (void)out_size; (void)ws_size;
  const float* x   = (const float*)d_in[0];
  const float* Wq  = (const float*)d_in[1];
  const float* Wk  = (const float*)d_in[2];
  const float* Wv  = (const float*)d_in[3];
  const float* Wo  = (const float*)d_in[4];
  const float* qg  = (const float*)d_in[5];

  char* ws = (char*)d_ws;
  bf16* xbf  = (bf16*)(ws);                         // 32 MB
  bf16* Wqkv = (bf16*)(ws + 33554432);              // 12 MB
  bf16* Wob  = (bf16*)(ws + 46137344);              //  8 MB
  bf16* Qb   = (bf16*)(ws + 54525952);              // 32 MB
  bf16* Kb   = (bf16*)(ws + 88080384);              //  8 MB
  bf16* Vb   = (bf16*)(ws + 96468992);              //  8 MB (transposed [b,kvh,d,s])
  bf16* Yb   = (bf16*)(ws + 104857600);             // 32 MB

  cast_all<<<13312, 256, 0, stream>>>(x, Wq, Wk, Wv, Wo, xbf, Wqkv, Wob);

  gemm8<1><<<dim3(NQKV/256, MROWS/256), 512, 0, stream>>>(
      xbf, Wqkv, nullptr, Qb, Kb, Vb, qg, NQKV, DIM);

  attn<<<dim3(8, BSZ*NHEADS), 256, 0, stream>>>(Qb, Kb, Vb, Yb);

  gemm8<0><<<dim3(DIM/256, MROWS/256), 512, 0, stream>>>(
      Yb, Wob, (float*)d_out, nullptr, nullptr, nullptr, nullptr, DIM, DIM);
}

// Round 5
// 439.114 us; speedup vs baseline: 1.0662x; 1.0662x over previous
//
#include <hip/hip_runtime.h>
#include <hip/hip_bf16.h>

typedef __hip_bfloat16 bf16;
typedef short s16x8 __attribute__((ext_vector_type(8)));
typedef float f32x4 __attribute__((ext_vector_type(4)));

#define DIM 2048
#define NHEADS 16
#define NKVH 4
#define HD 128
#define KVDIM 512
#define BSZ 4
#define SEQ 2048
#define MROWS (BSZ*SEQ)
#define NQKV (DIM+2*KVDIM)

// -------- async global->LDS, 16B per lane, wave-uniform LDS base --------
__device__ __forceinline__ void gld_lds16(const bf16* g, short* l) {
  __builtin_amdgcn_global_load_lds((__attribute__((address_space(1))) void*)(void*)g,
                                   (__attribute__((address_space(3))) void*)l, 16, 0, 0);
}

// -------- fused fp32 -> bf16 cast for all five tensors + RoPE cos/sin table --------
// groups of 8 elems: x 2097152 | Wq 524288 | Wk 131072 | Wv 131072 | Wo 524288
// then 131072 single-entry threads computing tab[s*64+d] = {cos, sin}
__global__ __launch_bounds__(256) void cast_all(
    const float* __restrict__ x,  const float* __restrict__ Wq,
    const float* __restrict__ Wk, const float* __restrict__ Wv,
    const float* __restrict__ Wo, bf16* __restrict__ xbf,
    bf16* __restrict__ Wqkv, bf16* __restrict__ Wob,
    float2* __restrict__ tab) {
  const int i = blockIdx.x*256 + threadIdx.x;      // 13824*256 = 3538944 exact
  if (i >= 3407872) {                              // RoPE table: 131072 entries
    const int i2 = i - 3407872;
    const int s = i2 >> 6, d = i2 & 63;
    float sn, cs;
    sincosf((float)s * exp2f((float)d * -0.20762050593046014f), &sn, &cs);
    tab[i2] = make_float2(cs, sn);
    return;
  }
  const float* src; bf16* dst; int j, o;
  if (i < 2097152)      { src = x;  dst = xbf;  j = i;           o = i; }
  else if (i < 2621440) { src = Wq; dst = Wqkv; j = i - 2097152; o = i - 2097152; }
  else if (i < 2752512) { src = Wk; dst = Wqkv; j = i - 2621440; o = i - 2097152; }
  else if (i < 2883584) { src = Wv; dst = Wqkv; j = i - 2752512; o = i - 2097152; }
  else                  { src = Wo; dst = Wob;  j = i - 2883584; o = i - 2883584; }
  const float4* s4 = (const float4*)src;
  float4 a = s4[2*j];
  float4 b = s4[2*j+1];
  union { bf16 h[8]; uint4 u; } pk;
  pk.h[0] = __float2bfloat16(a.x); pk.h[1] = __float2bfloat16(a.y);
  pk.h[2] = __float2bfloat16(a.z); pk.h[3] = __float2bfloat16(a.w);
  pk.h[4] = __float2bfloat16(b.x); pk.h[5] = __float2bfloat16(b.y);
  pk.h[6] = __float2bfloat16(b.z); pk.h[7] = __float2bfloat16(b.w);
  ((uint4*)dst)[o] = pk.u;
}

// ==================== 256x256 / BK=64 / 8-wave / 8-phase GEMM ====================
// C[M,N] = A[M,K] @ B[N,K]^T, bf16 in, fp32 acc. K must be 2048 (32 K-tiles).
// T1: bijective XCD swizzle. T2: st_16x32 LDS swizzle (inverse-permuted global src).
// T3+T4: 4 phases/K-tile, 1 half-tile staged/phase, single vmcnt(6)/K-tile.
// T5: s_setprio(1) around each 16-MFMA cluster.
// EPI=1: V via packed 8B stores; Q/K with FUSED RMSNorm+RoPE+gain:
//   - row sum-of-squares computed from acc REGISTERS (128 FMA + 4-level shfl),
//     halves combined via rs[4][2][128] LDS (one barrier) - no serial reduce.
//   - RoPE angles from precomputed table - no sincos on the GEMM critical path.
// EPI=0: fp32 C via wave-private LDS transpose -> 128B coalesced rows.

template<int MQ>
__device__ __forceinline__ void lda(s16x8 (&af)[4][2], const short* pa, int rds) {
#pragma unroll
  for (int fr = 0; fr < 4; fr++)
#pragma unroll
    for (int ks = 0; ks < 2; ks++)
      af[fr][ks] = *(const s16x8*)(pa + ((MQ*4 + fr)*2 + ks)*512 + rds);
}
template<int NQ>
__device__ __forceinline__ void ldb(s16x8 (&bfv)[2][2], const short* pb, int bsub, int rds) {
#pragma unroll
  for (int fc = 0; fc < 2; fc++)
#pragma unroll
    for (int ks = 0; ks < 2; ks++)
      bfv[fc][ks] = *(const s16x8*)(pb + (bsub + (NQ*2 + fc)*2 + ks)*512 + rds);
}
template<int MQ, int NQ>
__device__ __forceinline__ void mmq(f32x4 (&acc)[8][4], const s16x8 (&af)[4][2],
                                    const s16x8 (&bfv)[2][2]) {
#pragma unroll
  for (int fr = 0; fr < 4; fr++)
#pragma unroll
    for (int fc = 0; fc < 2; fc++)
#pragma unroll
      for (int ks = 0; ks < 2; ks++)
        acc[MQ*4+fr][NQ*2+fc] = __builtin_amdgcn_mfma_f32_16x16x32_bf16(
            af[fr][ks], bfv[fc][ks], acc[MQ*4+fr][NQ*2+fc], 0, 0, 0);
}

#define WV6 asm volatile("s_waitcnt vmcnt(6)" ::: "memory")
#define WV0 asm volatile("s_waitcnt vmcnt(0)" ::: "memory")
#define WVN ((void)0)
#define GBAR __builtin_amdgcn_s_barrier()
#define WLK asm volatile("s_waitcnt lgkmcnt(0)" ::: "memory")
#define PRI1 __builtin_amdgcn_s_setprio(1)
#define PRI0 __builtin_amdgcn_s_setprio(0)

#define KT(B_, T_, S1_, S2_, WVX) do {                                          \
    const short* pa = pAr[B_];                                                  \
    const short* pb = pBr[B_];                                                  \
    s16x8 af[4][2], b0f[2][2], b1f[2][2];                                       \
    /* phase 1: quad(0,0) */                                                    \
    lda<0>(af, pa, rds); ldb<0>(b0f, pb, bsub, rds);                            \
    if (S1_) {                                                                  \
      gld_lds16(Ab +      (long)((T_)+1)*64 + eA1, &L[1-(B_)][0][4096+wid512]); \
      gld_lds16(Ab + h1 + (long)((T_)+1)*64 + eA1, &L[1-(B_)][1][4096+wid512]); \
    }                                                                           \
    GBAR; WLK; PRI1; mmq<0,0>(acc, af, b0f); PRI0; GBAR;                        \
    /* phase 2: quad(0,1) */                                                    \
    ldb<1>(b1f, pb, bsub, rds);                                                 \
    if (S2_) {                                                                  \
      gld_lds16(Ab +      (long)((T_)+2)*64 + eA0, &L[B_][0][wid512]);          \
      gld_lds16(Ab + h1 + (long)((T_)+2)*64 + eA0, &L[B_][1][wid512]);          \
    }                                                                           \
    GBAR; WLK; PRI1; mmq<0,1>(acc, af, b1f); PRI0; GBAR;                        \
    /* phase 3: quad(1,0) */                                                    \
    lda<1>(af, pa, rds);                                                        \
    if (S2_) {                                                                  \
      gld_lds16(Bb + (long)((T_)+2)*64 + eA0, &L[B_][2][wid512]);               \
      gld_lds16(Bb + (long)((T_)+2)*64 + eA1, &L[B_][2][4096+wid512]);          \
    }                                                                           \
    GBAR; WLK; PRI1; mmq<1,0>(acc, af, b0f); PRI0; GBAR;                        \
    /* phase 4: quad(1,1) */                                                    \
    if (S2_) {                                                                  \
      gld_lds16(Bb + h1 + (long)((T_)+2)*64 + eA0, &L[B_][3][wid512]);          \
      gld_lds16(Bb + h1 + (long)((T_)+2)*64 + eA1, &L[B_][3][4096+wid512]);     \
    }                                                                           \
    WVX;                                                                        \
    GBAR; PRI1; mmq<1,1>(acc, af, b1f); PRI0; GBAR;                             \
  } while (0)

// EPI=0: plain fp32 C.  EPI=1: Q/K (fused norm+rope) / V^T[b,kvh,d,s].
template<int EPI>
__global__ __launch_bounds__(512, 2) void gemm8(
    const bf16* __restrict__ A, const bf16* __restrict__ Bm,
    float* __restrict__ Cf, bf16* __restrict__ Qo, bf16* __restrict__ Ko,
    bf16* __restrict__ Vo, const float* __restrict__ gain,
    const float2* __restrict__ tab, int N, int K) {
  // [buf][slot: A-half0, A-half1, B-half0, B-half1][16KB as shorts]
  __shared__ short L[2][4][8192] __attribute__((aligned(16)));
  __shared__ float rs[4][2][128];                 // per-region per-half row sumsq
  const int tid = threadIdx.x;
  const int lane = tid & 63, wid = tid >> 6;
  const int quad = lane >> 4, l15 = lane & 15;
  const int wm = wid >> 2, wn = wid & 3;          // 2 M-waves x 4 N-waves

  // ---- T1: bijective XCD swizzle (nwg % 8 == 0 for both grids) ----
  const int gx  = gridDim.x;
  const int lin = blockIdx.y * gx + blockIdx.x;
  const int cpx = (gx * gridDim.y) >> 3;
  const int swz = (lin & 7) * cpx + (lin >> 3);
  const int m0 = (swz / gx) * 256, n0 = (swz % gx) * 256;

  // ---- swizzled ds_read lane offset (shorts within a half-tile slot) ----
  const int rds = l15*32 + ((quad*8) ^ ((l15 & 8) << 1));
  const int bsub = (wn & 1) * 8;                  // B strip within its half: 8 subtiles

  // ---- staging source offsets (inverse-swizzled global address, linear LDS dest) ----
  const int colx = ((lane & 3) * 8) ^ ((lane >> 5) << 4);
  const int gc   = ((wid & 1) << 5) + colx;
  const int gr0  = ((wid >> 1) << 4) + (lane >> 2);
  const long eA0 = (long)gr0 * K + gc;            // j=0 chunk: rows 0-63 of half
  const long eA1 = eA0 + 64L * K;                 // j=1 chunk: rows 64-127
  const int wid512 = wid * 512;
  const bf16* Ab = A  + (long)m0 * K;
  const bf16* Bb = Bm + (long)n0 * K;
  const long h1 = 128L * K;                       // half-1 row offset

  const short* pAr[2] = { &L[0][wm][0], &L[1][wm][0] };
  const short* pBr[2] = { &L[0][2 + (wn >> 1)][0], &L[1][2 + (wn >> 1)][0] };

  f32x4 acc[8][4] = {};

  // ---- prologue: K0 complete (8 chunks) + K1 partial (A-L0s, B: 6 chunks) ----
  gld_lds16(Ab + eA0,           &L[0][0][wid512]);
  gld_lds16(Ab + eA1,           &L[0][0][4096 + wid512]);
  gld_lds16(Ab + h1 + eA0,      &L[0][1][wid512]);
  gld_lds16(Ab + h1 + eA1,      &L[0][1][4096 + wid512]);
  gld_lds16(Bb + eA0,           &L[0][2][wid512]);
  gld_lds16(Bb + eA1,           &L[0][2][4096 + wid512]);
  gld_lds16(Bb + h1 + eA0,      &L[0][3][wid512]);
  gld_lds16(Bb + h1 + eA1,      &L[0][3][4096 + wid512]);
  gld_lds16(Ab + 64 + eA0,      &L[1][0][wid512]);
  gld_lds16(Ab + h1 + 64 + eA0, &L[1][1][wid512]);
  gld_lds16(Bb + 64 + eA0,      &L[1][2][wid512]);
  gld_lds16(Bb + 64 + eA1,      &L[1][2][4096 + wid512]);
  gld_lds16(Bb + h1 + 64 + eA0, &L[1][3][wid512]);
  gld_lds16(Bb + h1 + 64 + eA1, &L[1][3][4096 + wid512]);
  WV6;   // K0's 8 landed; K1's 6 in flight
  GBAR;

  // ---- main loop: 32 K-tiles (K=2048), steady pairs then drained tail ----
  for (int t = 0; t < 30; t += 2) {
    KT(0, t,   1, 1, WV6);
    KT(1, t+1, 1, 1, WV6);
  }
  KT(0, 30, 1, 0, WV0);   // WV0 drains all staging -> LDS reusable below
  KT(1, 31, 0, 0, WVN);

  // ---- epilogue ----
  const int colg0 = n0 + wn*64;                   // wave's first output column
  const int bb = (m0 + wm*128) >> 11;             // batch (tile never crosses)
  const int sb = (m0 + wm*128) & (SEQ-1);         // seq base of wave's 128 rows
  if (EPI == 0) {
    // fp32 C via wave-private LDS transpose, two 32-col halves -> 128B rows
    float* ew = (float*)(&L[0][0][0]) + wid*4096; // 16KB slice: [128 rows][32 cols]
    const int rowb = m0 + wm*128;
    const int rr = lane >> 3, c4 = (lane & 7)*4;
#pragma unroll
    for (int half = 0; half < 2; half++) {
#pragma unroll
      for (int mi = 0; mi < 8; mi++)
#pragma unroll
        for (int nj2 = 0; nj2 < 2; nj2++)
#pragma unroll
          for (int r = 0; r < 4; r++)
            ew[(mi*16 + quad*4 + r)*32 + nj2*16 + l15] = acc[mi][half*2 + nj2][r];
      asm volatile("" ::: "memory");              // pin write->read order (in-wave)
#pragma unroll
      for (int it = 0; it < 16; it++) {
        const int row = it*8 + rr;
        float4 v = *(const float4*)&ew[row*32 + c4];
        *(float4*)(Cf + (long)(rowb + row)*N + colg0 + half*32 + c4) = v;
      }
      asm volatile("" ::: "memory");              // pin read->next-half-write order
    }
  } else if (n0 >= DIM + KVDIM) {
    // V block: 4 s-contiguous rows per acc quad -> one 8B store each
    const int cv = colg0 - (DIM + KVDIM);
    const int h  = cv >> 7;                       // wave-uniform
    const int db = cv & 127;
    bf16* vb = Vo + ((long)(bb*NKVH + h)*HD)*SEQ + sb;
#pragma unroll
    for (int mi = 0; mi < 8; mi++)
#pragma unroll
      for (int nj = 0; nj < 4; nj++) {
        const int d = db + nj*16 + l15;
        union { bf16 h4[4]; unsigned long long u; } pk;
        pk.h4[0] = __float2bfloat16(acc[mi][nj][0]);
        pk.h4[1] = __float2bfloat16(acc[mi][nj][1]);
        pk.h4[2] = __float2bfloat16(acc[mi][nj][2]);
        pk.h4[3] = __float2bfloat16(acc[mi][nj][3]);
        *(unsigned long long*)(vb + (long)d*SEQ + mi*16 + quad*4) = pk.u;
      }
  } else {
    // Q/K block: FUSED RMSNorm + RoPE (+ q_gain*1/sqrt(HD)).
    // (1) per-row sum of squares from acc regs: lane partial over its 4 cols,
    //     4-level shfl over the 16 lanes sharing the row, halves -> rs LDS.
    float p[8][4];
#pragma unroll
    for (int mi = 0; mi < 8; mi++)
#pragma unroll
      for (int r = 0; r < 4; r++) {
        float v = acc[mi][0][r]*acc[mi][0][r];
        v += acc[mi][1][r]*acc[mi][1][r];
        v += acc[mi][2][r]*acc[mi][2][r];
        v += acc[mi][3][r]*acc[mi][3][r];
#pragma unroll
        for (int off = 1; off < 16; off <<= 1) v += __shfl_xor(v, off);
        p[mi][r] = v;
      }
    const int reg = wm*2 + (wn >> 1);
    const int half = wn & 1;
    if (l15 == 0) {
#pragma unroll
      for (int mi = 0; mi < 8; mi++)
#pragma unroll
        for (int r = 0; r < 4; r++)
          rs[reg][half][mi*16 + quad*4 + r] = p[mi][r];
    }
    // (2) transpose into shared region [128 rows][128 head-cols] bf16 = 32KB
    short* Ls = &L[0][0][0];
    short* rw = Ls + reg*16384;
    const int cw = half*64;
#pragma unroll
    for (int mi = 0; mi < 8; mi++)
#pragma unroll
      for (int nj = 0; nj < 4; nj++)
#pragma unroll
        for (int r = 0; r < 4; r++) {
          bf16 hv = __float2bfloat16(acc[mi][nj][r]);
          rw[(mi*16 + quad*4 + r)*128 + cw + nj*16 + l15] = *(short*)&hv;
        }
    __syncthreads();
    // (3) normalize + rope 64 rows (this wave's half of the region)
    const short* rg = Ls + reg*16384;
    const int row0 = half*64;
    float g; bf16* gb;
    if (n0 < DIM) {
      const int h = (n0 >> 7) + (wn >> 1);
      g = gain[h] * 0.08838834764831845f;   // fold softmax scale 1/sqrt(128) into q
      gb = Qo + (long)(bb*NHEADS + h)*SEQ*HD;
    } else {
      const int h = ((n0 - DIM) >> 7) + (wn >> 1);
      g = 1.0f;
      gb = Ko + (long)(bb*NKVH + h)*SEQ*HD;
    }
    for (int rI = 0; rI < 64; rI++) {
      const int row = row0 + rI;
      const float x1 = __bfloat162float(*(const bf16*)&rg[row*128 + lane]);
      const float x2 = __bfloat162float(*(const bf16*)&rg[row*128 + 64 + lane]);
      const float ssum = rs[reg][0][row] + rs[reg][1][row];
      const float rn = rsqrtf(ssum*(1.0f/128.0f) + 1.1920928955078125e-07f);
      const int s = sb + row;
      const float2 cs = tab[s*64 + lane];
      const float q1 = x1*rn, q2 = x2*rn;
      bf16* pr = gb + (long)s*HD;
      pr[lane]      = __float2bfloat16((q1*cs.x + q2*cs.y)*g);
      pr[64 + lane] = __float2bfloat16((q2*cs.x - q1*cs.y)*g);
    }
  }
}

// -------- causal flash attention: S^T form, fixed-shift softmax, qt-paired --------
// T14 async-STAGE split; T5 setprio; T1 XCD swizzle.
__global__ __launch_bounds__(256, 2) void attn(
    const bf16* __restrict__ Qb, const bf16* __restrict__ Kb,
    const bf16* __restrict__ Vtg, bf16* __restrict__ Yb) {
  __shared__ short Kt[64*136]  __attribute__((aligned(16)));  // [key][k] pad->136
  __shared__ short Vt[128*72]  __attribute__((aligned(16)));  // [d][key] pad->72
  __shared__ short Pt[4*2304]  __attribute__((aligned(16)));  // per-wave, per-group [16 q][72]

  const int tid = threadIdx.x;
  const int lane = tid & 63, wid = tid >> 6;
  const int quad = lane >> 4, l15 = lane & 15;
  const int lin = blockIdx.y*8 + blockIdx.x;    // 512 blocks, %8==0
  const int swz = (lin & 7)*64 + (lin >> 3);    // bijective XCD chunking
  const int xb = swz & 7;                       // 0..7
  const int bh = swz >> 3;
  const int b = bh >> 4, h = bh & 15, kvh = h >> 2;

  const bf16* kbase = Kb  + (long)(b*NKVH + kvh)*SEQ*HD;
  const bf16* vbase = Vtg + (long)(b*NKVH + kvh)*HD*SEQ;   // [d][s]
  short* pw0 = Pt + wid*2304;
  short* pw1 = pw0 + 1152;
  const int krow = tid >> 4, kc = (tid & 15)*8;
  const int vrow = tid >> 3, vc = (tid & 7)*8;

#define LOADK(KT_) do {                                                        \
    kr0 = *(const uint4*)(kbase + (long)((KT_)*64 +  0 + krow)*HD + kc);       \
    kr1 = *(const uint4*)(kbase + (long)((KT_)*64 + 16 + krow)*HD + kc);       \
    kr2 = *(const uint4*)(kbase + (long)((KT_)*64 + 32 + krow)*HD + kc);       \
    kr3 = *(const uint4*)(kbase + (long)((KT_)*64 + 48 + krow)*HD + kc);       \
  } while (0)
#define LOADV(KT_) do {                                                        \
    vr0 = *(const uint4*)(vbase + (long)(  0 + vrow)*SEQ + (KT_)*64 + vc);     \
    vr1 = *(const uint4*)(vbase + (long)( 32 + vrow)*SEQ + (KT_)*64 + vc);     \
    vr2 = *(const uint4*)(vbase + (long)( 64 + vrow)*SEQ + (KT_)*64 + vc);     \
    vr3 = *(const uint4*)(vbase + (long)( 96 + vrow)*SEQ + (KT_)*64 + vc);     \
  } while (0)

  for (int phase = 0; phase < 2; phase++) {
    const int qt = phase ? xb : (15 - xb);      // heavy first
    const int q0 = qt*128 + wid*16 + l15;       // group 0 query
    const int q1 = q0 + 64;                     // group 1 query
    const bf16* qr0 = Qb + ((long)(b*NHEADS + h)*SEQ + q0)*HD + quad*8;
    s16x8 qa0[4], qa1[4];
#pragma unroll
    for (int st = 0; st < 4; st++) {
      qa0[st] = *(const s16x8*)(qr0 + st*32);
      qa1[st] = *(const s16x8*)(qr0 + 64*HD + st*32);
    }

    f32x4 o0[8] = {}, o1[8] = {};
    float li0 = 0.0f, li1 = 0.0f;
    const int ktiles = 2*qt + 2;

    uint4 kr0, kr1, kr2, kr3, vr0, vr1, vr2, vr3;
    LOADK(0); LOADV(0);                          // prologue issue (exposed once)

    for (int kt = 0; kt < ktiles; kt++) {
      __syncthreads();                           // all waves done reading prev tile
      // publish tile kt (compiler inserts the vmcnt wait before first ds_write)
      *(uint4*)&Kt[( 0 + krow)*136 + kc] = kr0;
      *(uint4*)&Kt[(16 + krow)*136 + kc] = kr1;
      *(uint4*)&Kt[(32 + krow)*136 + kc] = kr2;
      *(uint4*)&Kt[(48 + krow)*136 + kc] = kr3;
      *(uint4*)&Vt[(  0 + vrow)*72 + vc] = vr0;
      *(uint4*)&Vt[( 32 + vrow)*72 + vc] = vr1;
      *(uint4*)&Vt[( 64 + vrow)*72 + vc] = vr2;
      *(uint4*)&Vt[( 96 + vrow)*72 + vc] = vr3;
      __syncthreads();                           // tile kt visible
      if (kt + 1 < ktiles) { LOADK(kt+1); LOADV(kt+1); }  // T14: hide under compute

      // S^T = K Q^T for both groups; kf frags shared
      f32x4 s0[4] = {}, s1[4] = {};
#pragma unroll
      for (int nt = 0; nt < 4; nt++) {
        s16x8 kf[4];
#pragma unroll
        for (int st = 0; st < 4; st++)
          kf[st] = *(const s16x8*)&Kt[(nt*16 + l15)*136 + st*32 + quad*8];
        PRI1;
#pragma unroll
        for (int st = 0; st < 4; st++) {
          s0[nt] = __builtin_amdgcn_mfma_f32_16x16x32_bf16(kf[st], qa0[st], s0[nt], 0, 0, 0);
          s1[nt] = __builtin_amdgcn_mfma_f32_16x16x32_bf16(kf[st], qa1[st], s1[nt], 0, 0, 0);
        }
        PRI0;
      }

      // fixed-shift softmax: P = exp(s - 12); |s|<11.5 provably (rms-normed q,k)
      const bool d0 = (kt >= 2*qt);
      const bool d1 = (kt >  2*qt);
      const int tb = kt*64 + quad*4;
      union { bf16 h[16]; unsigned long long u[4]; } p0, p1;
      float rs0 = 0.0f, rs1 = 0.0f;
#pragma unroll
      for (int nt = 0; nt < 4; nt++) {
#pragma unroll
        for (int r = 0; r < 4; r++) {
          const int t = tb + nt*16 + r;
          float v0 = s0[nt][r], v1 = s1[nt][r];
          if (d0 && (t > q0)) v0 = -1e30f;
          if (d1 && (t > q1)) v1 = -1e30f;
          const float e0 = __expf(v0 - 12.0f);
          const float e1 = __expf(v1 - 12.0f);
          rs0 += e0; rs1 += e1;
          p0.h[nt*4+r] = __float2bfloat16(e0);
          p1.h[nt*4+r] = __float2bfloat16(e1);
        }
      }
      li0 += rs0; li1 += rs1;
#pragma unroll
      for (int nt = 0; nt < 4; nt++) {
        *(unsigned long long*)&pw0[l15*72 + nt*16 + quad*4] = p0.u[nt];
        *(unsigned long long*)&pw1[l15*72 + nt*16 + quad*4] = p1.u[nt];
      }

      // O^T += V^T P^T for both groups; vf frags shared
#pragma unroll
      for (int st = 0; st < 2; st++) {
        s16x8 pf0 = *(const s16x8*)&pw0[l15*72 + st*32 + quad*8];
        s16x8 pf1 = *(const s16x8*)&pw1[l15*72 + st*32 + quad*8];
        PRI1;
#pragma unroll
        for (int dt = 0; dt < 8; dt++) {
          s16x8 vf = *(const s16x8*)&Vt[(dt*16 + l15)*72 + st*32 + quad*8];
          o0[dt] = __builtin_amdgcn_mfma_f32_16x16x32_bf16(vf, pf0, o0[dt], 0, 0, 0);
          o1[dt] = __builtin_amdgcn_mfma_f32_16x16x32_bf16(vf, pf1, o1[dt], 0, 0, 0);
        }
        PRI0;
      }
    }

    // finalize li (once per phase), then transpose O^T -> O via wave-private Pt slice
    li0 += __shfl_xor(li0, 16); li0 += __shfl_xor(li0, 32);
    li1 += __shfl_xor(li1, 16); li1 += __shfl_xor(li1, 32);
    const float inv0 = 1.0f / li0, inv1 = 1.0f / li1;

    short* ep = pw0;
#pragma unroll
    for (int g = 0; g < 2; g++) {
      const float inv = g ? inv1 : inv0;
      const f32x4* o = g ? o1 : o0;
      const int qg = g ? q1 : q0;
#pragma unroll
      for (int dt = 0; dt < 8; dt++) {
        union { bf16 h[4]; unsigned long long u; } pk;
        pk.h[0] = __float2bfloat16(o[dt][0]*inv);
        pk.h[1] = __float2bfloat16(o[dt][1]*inv);
        pk.h[2] = __float2bfloat16(o[dt][2]*inv);
        pk.h[3] = __float2bfloat16(o[dt][3]*inv);
        *(unsigned long long*)&ep[l15*136 + dt*16 + quad*4] = pk.u;
      }
      bf16* yb = Yb + ((long)(b*SEQ + qg - l15))*DIM + h*HD;
#pragma unroll
      for (int p = 0; p < 4; p++) {
        const int c = quad + 4*p;
        uint4 yv = *(const uint4*)&ep[l15*136 + c*8];
        *(uint4*)&yb[(long)l15*DIM + c*8] = yv;
      }
    }
  }
#undef LOADK
#undef LOADV
}

extern "C" void kernel_launch(void* const* d_in, const int* in_sizes, int n_in,
                              void* d_out, int out_size, void* d_ws, size_t ws_size,
                              hipStream_t stream) {
  (void)in_sizes; (void)n_in; (void)out_size; (void)ws_size;
  const float* x   = (const float*)d_in[0];
  const float* Wq  = (const float*)d_in[1];
  const float* Wk  = (const float*)d_in[2];
  const float* Wv  = (const float*)d_in[3];
  const float* Wo  = (const float*)d_in[4];
  const float* qg  = (const float*)d_in[5];

  char* ws = (char*)d_ws;
  bf16* xbf  = (bf16*)(ws);                         // 32 MB
  bf16* Wqkv = (bf16*)(ws + 33554432);              // 12 MB
  bf16* Wob  = (bf16*)(ws + 46137344);              //  8 MB
  bf16* Qb   = (bf16*)(ws + 54525952);              // 32 MB
  bf16* Kb   = (bf16*)(ws + 88080384);              //  8 MB
  bf16* Vb   = (bf16*)(ws + 96468992);              //  8 MB (transposed [b,kvh,d,s])
  bf16* Yb   = (bf16*)(ws + 104857600);             // 32 MB
  // RoPE table aliases Yb (1MB): dead before attn writes Yb, used only in QKV epilogue
  float2* tab = (float2*)(ws + 104857600);

  cast_all<<<13824, 256, 0, stream>>>(x, Wq, Wk, Wv, Wo, xbf, Wqkv, Wob, tab);

  gemm8<1><<<dim3(NQKV/256, MROWS/256), 512, 0, stream>>>(
      xbf, Wqkv, nullptr, Qb, Kb, Vb, qg, tab, NQKV, DIM);

  attn<<<dim3(8, BSZ*NHEADS), 256, 0, stream>>>(Qb, Kb, Vb, Yb);

  gemm8<0><<<dim3(DIM/256, MROWS/256), 512, 0, stream>>>(
      Yb, Wob, (float*)d_out, nullptr, nullptr, nullptr, nullptr, nullptr, DIM, DIM);
}

// Round 7
// 429.015 us; speedup vs baseline: 1.0913x; 1.0235x over previous
//
#include <hip/hip_runtime.h>
#include <hip/hip_bf16.h>

typedef __hip_bfloat16 bf16;
typedef short s16x8 __attribute__((ext_vector_type(8)));
typedef float f32x4 __attribute__((ext_vector_type(4)));

#define DIM 2048
#define NHEADS 16
#define NKVH 4
#define HD 128
#define KVDIM 512
#define BSZ 4
#define SEQ 2048
#define MROWS (BSZ*SEQ)
#define NQKV (DIM+2*KVDIM)

// -------- async global->LDS, 16B per lane, wave-uniform LDS base --------
__device__ __forceinline__ void gld_lds16(const bf16* g, short* l) {
  __builtin_amdgcn_global_load_lds((__attribute__((address_space(1))) void*)(void*)g,
                                   (__attribute__((address_space(3))) void*)l, 16, 0, 0);
}

__device__ __forceinline__ float bfu(ushort u) {
  return __bfloat162float(*(const bf16*)&u);
}
__device__ __forceinline__ ushort fbu(float f) {
  bf16 h = __float2bfloat16(f);
  return *(const ushort*)&h;
}

// -------- fused fp32 -> bf16 cast for all five tensors + RoPE cos/sin table --------
// groups of 8 elems: x 2097152 | Wq 524288 | Wk 131072 | Wv 131072 | Wo 524288
// then 131072 single-entry threads computing tab[s*64+d] = {cos, sin}
__global__ __launch_bounds__(256) void cast_all(
    const float* __restrict__ x,  const float* __restrict__ Wq,
    const float* __restrict__ Wk, const float* __restrict__ Wv,
    const float* __restrict__ Wo, bf16* __restrict__ xbf,
    bf16* __restrict__ Wqkv, bf16* __restrict__ Wob,
    float2* __restrict__ tab) {
  const int i = blockIdx.x*256 + threadIdx.x;      // 13824*256 = 3538944 exact
  if (i >= 3407872) {                              // RoPE table: 131072 entries
    const int i2 = i - 3407872;
    const int s = i2 >> 6, d = i2 & 63;
    float sn, cs;
    sincosf((float)s * exp2f((float)d * -0.20762050593046014f), &sn, &cs);
    tab[i2] = make_float2(cs, sn);
    return;
  }
  const float* src; bf16* dst; int j, o;
  if (i < 2097152)      { src = x;  dst = xbf;  j = i;           o = i; }
  else if (i < 2621440) { src = Wq; dst = Wqkv; j = i - 2097152; o = i - 2097152; }
  else if (i < 2752512) { src = Wk; dst = Wqkv; j = i - 2621440; o = i - 2097152; }
  else if (i < 2883584) { src = Wv; dst = Wqkv; j = i - 2752512; o = i - 2097152; }
  else                  { src = Wo; dst = Wob;  j = i - 2883584; o = i - 2883584; }
  const float4* s4 = (const float4*)src;
  float4 a = s4[2*j];
  float4 b = s4[2*j+1];
  union { bf16 h[8]; uint4 u; } pk;
  pk.h[0] = __float2bfloat16(a.x); pk.h[1] = __float2bfloat16(a.y);
  pk.h[2] = __float2bfloat16(a.z); pk.h[3] = __float2bfloat16(a.w);
  pk.h[4] = __float2bfloat16(b.x); pk.h[5] = __float2bfloat16(b.y);
  pk.h[6] = __float2bfloat16(b.z); pk.h[7] = __float2bfloat16(b.w);
  ((uint4*)dst)[o] = pk.u;
}

// ==================== 256x256 / BK=64 / 8-wave / 8-phase GEMM ====================
// C[M,N] = A[M,K] @ B[N,K]^T, bf16 in, fp32 acc. K must be 2048 (32 K-tiles).
// T1: bijective XCD swizzle. T2: st_16x32 LDS swizzle (inverse-permuted global src).
// T3+T4: 4 phases/K-tile, 1 half-tile staged/phase, single vmcnt(6)/K-tile.
// T5: s_setprio(1) around each 16-MFMA cluster.
// Round-5 lesson: norm/rope fusion into the epilogue is net-negative (serial
// latency on 320 block-tails > standalone memory-bound kernel). Epilogue kept
// minimal: Q/K raw bf16 via LDS transpose -> 16B stores; V packed 8B stores.

template<int MQ>
__device__ __forceinline__ void lda(s16x8 (&af)[4][2], const short* pa, int rds) {
#pragma unroll
  for (int fr = 0; fr < 4; fr++)
#pragma unroll
    for (int ks = 0; ks < 2; ks++)
      af[fr][ks] = *(const s16x8*)(pa + ((MQ*4 + fr)*2 + ks)*512 + rds);
}
template<int NQ>
__device__ __forceinline__ void ldb(s16x8 (&bfv)[2][2], const short* pb, int bsub, int rds) {
#pragma unroll
  for (int fc = 0; fc < 2; fc++)
#pragma unroll
    for (int ks = 0; ks < 2; ks++)
      bfv[fc][ks] = *(const s16x8*)(pb + (bsub + (NQ*2 + fc)*2 + ks)*512 + rds);
}
template<int MQ, int NQ>
__device__ __forceinline__ void mmq(f32x4 (&acc)[8][4], const s16x8 (&af)[4][2],
                                    const s16x8 (&bfv)[2][2]) {
#pragma unroll
  for (int fr = 0; fr < 4; fr++)
#pragma unroll
    for (int fc = 0; fc < 2; fc++)
#pragma unroll
      for (int ks = 0; ks < 2; ks++)
        acc[MQ*4+fr][NQ*2+fc] = __builtin_amdgcn_mfma_f32_16x16x32_bf16(
            af[fr][ks], bfv[fc][ks], acc[MQ*4+fr][NQ*2+fc], 0, 0, 0);
}

#define WV6 asm volatile("s_waitcnt vmcnt(6)" ::: "memory")
#define WV0 asm volatile("s_waitcnt vmcnt(0)" ::: "memory")
#define WVN ((void)0)
#define GBAR __builtin_amdgcn_s_barrier()
#define WLK asm volatile("s_waitcnt lgkmcnt(0)" ::: "memory")
#define PRI1 __builtin_amdgcn_s_setprio(1)
#define PRI0 __builtin_amdgcn_s_setprio(0)

#define KT(B_, T_, S1_, S2_, WVX) do {                                          \
    const short* pa = pAr[B_];                                                  \
    const short* pb = pBr[B_];                                                  \
    s16x8 af[4][2], b0f[2][2], b1f[2][2];                                       \
    /* phase 1: quad(0,0) */                                                    \
    lda<0>(af, pa, rds); ldb<0>(b0f, pb, bsub, rds);                            \
    if (S1_) {                                                                  \
      gld_lds16(Ab +      (long)((T_)+1)*64 + eA1, &L[1-(B_)][0][4096+wid512]); \
      gld_lds16(Ab + h1 + (long)((T_)+1)*64 + eA1, &L[1-(B_)][1][4096+wid512]); \
    }                                                                           \
    GBAR; WLK; PRI1; mmq<0,0>(acc, af, b0f); PRI0; GBAR;                        \
    /* phase 2: quad(0,1) */                                                    \
    ldb<1>(b1f, pb, bsub, rds);                                                 \
    if (S2_) {                                                                  \
      gld_lds16(Ab +      (long)((T_)+2)*64 + eA0, &L[B_][0][wid512]);          \
      gld_lds16(Ab + h1 + (long)((T_)+2)*64 + eA0, &L[B_][1][wid512]);          \
    }                                                                           \
    GBAR; WLK; PRI1; mmq<0,1>(acc, af, b1f); PRI0; GBAR;                        \
    /* phase 3: quad(1,0) */                                                    \
    lda<1>(af, pa, rds);                                                        \
    if (S2_) {                                                                  \
      gld_lds16(Bb + (long)((T_)+2)*64 + eA0, &L[B_][2][wid512]);               \
      gld_lds16(Bb + (long)((T_)+2)*64 + eA1, &L[B_][2][4096+wid512]);          \
    }                                                                           \
    GBAR; WLK; PRI1; mmq<1,0>(acc, af, b0f); PRI0; GBAR;                        \
    /* phase 4: quad(1,1) */                                                    \
    if (S2_) {                                                                  \
      gld_lds16(Bb + h1 + (long)((T_)+2)*64 + eA0, &L[B_][3][wid512]);          \
      gld_lds16(Bb + h1 + (long)((T_)+2)*64 + eA1, &L[B_][3][4096+wid512]);     \
    }                                                                           \
    WVX;                                                                        \
    GBAR; PRI1; mmq<1,1>(acc, af, b1f); PRI0; GBAR;                             \
  } while (0)

// EPI=0: plain fp32 C.  EPI=1: scatter bf16 into Q[b,h,s,d]/K[b,h,s,d]/V^T[b,kvh,d,s].
template<int EPI>
__global__ __launch_bounds__(512, 2) void gemm8(
    const bf16* __restrict__ A, const bf16* __restrict__ Bm,
    float* __restrict__ Cf, bf16* __restrict__ Qo, bf16* __restrict__ Ko,
    bf16* __restrict__ Vo, int N, int K) {
  // [buf][slot: A-half0, A-half1, B-half0, B-half1][16KB as shorts]
  __shared__ short L[2][4][8192] __attribute__((aligned(16)));
  const int tid = threadIdx.x;
  const int lane = tid & 63, wid = tid >> 6;
  const int quad = lane >> 4, l15 = lane & 15;
  const int wm = wid >> 2, wn = wid & 3;          // 2 M-waves x 4 N-waves

  // ---- T1: bijective XCD swizzle (nwg % 8 == 0 for both grids) ----
  const int gx  = gridDim.x;
  const int lin = blockIdx.y * gx + blockIdx.x;
  const int cpx = (gx * gridDim.y) >> 3;
  const int swz = (lin & 7) * cpx + (lin >> 3);
  const int m0 = (swz / gx) * 256, n0 = (swz % gx) * 256;

  // ---- swizzled ds_read lane offset (shorts within a half-tile slot) ----
  const int rds = l15*32 + ((quad*8) ^ ((l15 & 8) << 1));
  const int bsub = (wn & 1) * 8;                  // B strip within its half: 8 subtiles

  // ---- staging source offsets (inverse-swizzled global address, linear LDS dest) ----
  const int colx = ((lane & 3) * 8) ^ ((lane >> 5) << 4);
  const int gc   = ((wid & 1) << 5) + colx;
  const int gr0  = ((wid >> 1) << 4) + (lane >> 2);
  const long eA0 = (long)gr0 * K + gc;            // j=0 chunk: rows 0-63 of half
  const long eA1 = eA0 + 64L * K;                 // j=1 chunk: rows 64-127
  const int wid512 = wid * 512;
  const bf16* Ab = A  + (long)m0 * K;
  const bf16* Bb = Bm + (long)n0 * K;
  const long h1 = 128L * K;                       // half-1 row offset

  const short* pAr[2] = { &L[0][wm][0], &L[1][wm][0] };
  const short* pBr[2] = { &L[0][2 + (wn >> 1)][0], &L[1][2 + (wn >> 1)][0] };

  f32x4 acc[8][4] = {};

  // ---- prologue: K0 complete (8 chunks) + K1 partial (A-L0s, B: 6 chunks) ----
  gld_lds16(Ab + eA0,           &L[0][0][wid512]);
  gld_lds16(Ab + eA1,           &L[0][0][4096 + wid512]);
  gld_lds16(Ab + h1 + eA0,      &L[0][1][wid512]);
  gld_lds16(Ab + h1 + eA1,      &L[0][1][4096 + wid512]);
  gld_lds16(Bb + eA0,           &L[0][2][wid512]);
  gld_lds16(Bb + eA1,           &L[0][2][4096 + wid512]);
  gld_lds16(Bb + h1 + eA0,      &L[0][3][wid512]);
  gld_lds16(Bb + h1 + eA1,      &L[0][3][4096 + wid512]);
  gld_lds16(Ab + 64 + eA0,      &L[1][0][wid512]);
  gld_lds16(Ab + h1 + 64 + eA0, &L[1][1][wid512]);
  gld_lds16(Bb + 64 + eA0,      &L[1][2][wid512]);
  gld_lds16(Bb + 64 + eA1,      &L[1][2][4096 + wid512]);
  gld_lds16(Bb + h1 + 64 + eA0, &L[1][3][wid512]);
  gld_lds16(Bb + h1 + 64 + eA1, &L[1][3][4096 + wid512]);
  WV6;   // K0's 8 landed; K1's 6 in flight
  GBAR;

  // ---- main loop: 32 K-tiles (K=2048), steady pairs then drained tail ----
  for (int t = 0; t < 30; t += 2) {
    KT(0, t,   1, 1, WV6);
    KT(1, t+1, 1, 1, WV6);
  }
  KT(0, 30, 1, 0, WV0);   // WV0 drains all staging -> LDS reusable below
  KT(1, 31, 0, 0, WVN);

  // ---- epilogue ----
  const int colg0 = n0 + wn*64;                   // wave's first output column
  const int bb = (m0 + wm*128) >> 11;             // batch (tile never crosses)
  const int sb = (m0 + wm*128) & (SEQ-1);         // seq base of wave's 128 rows
  if (EPI == 0) {
    // fp32 C via wave-private LDS transpose, two 32-col halves -> 128B rows
    float* ew = (float*)(&L[0][0][0]) + wid*4096; // 16KB slice: [128 rows][32 cols]
    const int rowb = m0 + wm*128;
    const int rr = lane >> 3, c4 = (lane & 7)*4;
#pragma unroll
    for (int half = 0; half < 2; half++) {
#pragma unroll
      for (int mi = 0; mi < 8; mi++)
#pragma unroll
        for (int nj2 = 0; nj2 < 2; nj2++)
#pragma unroll
          for (int r = 0; r < 4; r++)
            ew[(mi*16 + quad*4 + r)*32 + nj2*16 + l15] = acc[mi][half*2 + nj2][r];
      asm volatile("" ::: "memory");              // pin write->read order (in-wave)
#pragma unroll
      for (int it = 0; it < 16; it++) {
        const int row = it*8 + rr;
        float4 v = *(const float4*)&ew[row*32 + c4];
        *(float4*)(Cf + (long)(rowb + row)*N + colg0 + half*32 + c4) = v;
      }
      asm volatile("" ::: "memory");              // pin read->next-half-write order
    }
  } else if (n0 >= DIM + KVDIM) {
    // V block: 4 s-contiguous rows per acc quad -> one 8B store each
    const int cv = colg0 - (DIM + KVDIM);
    const int h  = cv >> 7;                       // wave-uniform
    const int db = cv & 127;
    bf16* vb = Vo + ((long)(bb*NKVH + h)*HD)*SEQ + sb;
#pragma unroll
    for (int mi = 0; mi < 8; mi++)
#pragma unroll
      for (int nj = 0; nj < 4; nj++) {
        const int d = db + nj*16 + l15;
        union { bf16 h4[4]; unsigned long long u; } pk;
        pk.h4[0] = __float2bfloat16(acc[mi][nj][0]);
        pk.h4[1] = __float2bfloat16(acc[mi][nj][1]);
        pk.h4[2] = __float2bfloat16(acc[mi][nj][2]);
        pk.h4[3] = __float2bfloat16(acc[mi][nj][3]);
        *(unsigned long long*)(vb + (long)d*SEQ + mi*16 + quad*4) = pk.u;
      }
  } else {
    // Q/K region: wave-private LDS transpose -> coalesced 16B row stores
    short* ew = &L[0][0][0] + wid*8192;           // 16KB slice: [row 0..127][col 0..63]
#pragma unroll
    for (int mi = 0; mi < 8; mi++)
#pragma unroll
      for (int nj = 0; nj < 4; nj++)
#pragma unroll
        for (int r = 0; r < 4; r++) {
          bf16 hv = __float2bfloat16(acc[mi][nj][r]);
          ew[(mi*16 + quad*4 + r)*64 + nj*16 + l15] = *(short*)&hv;
        }
    asm volatile("" ::: "memory");                // pin write->read order
    bf16* gb;
    if (colg0 < DIM) gb = Qo + (long)(bb*NHEADS + (colg0 >> 7))*SEQ*HD;
    else             gb = Ko + (long)(bb*NKVH + ((colg0 - DIM) >> 7))*SEQ*HD;
    const int db = colg0 & 127;                   // 0 or 64
    const int rr = lane >> 3, c8 = (lane & 7)*8;
#pragma unroll
    for (int it = 0; it < 16; it++) {
      const int row = it*8 + rr;
      uint4 v = *(const uint4*)&ew[row*64 + c8];
      *(uint4*)(gb + (long)(sb + row)*HD + db + c8) = v;
    }
  }
}

// -------- RMSNorm + RoPE (+ q_gain * 1/sqrt(HD)) in-place on bf16 [rows][128] --------
// 2 rows per wave (32 lanes each); 4B loads/stores per lane; cos/sin from table
// (L2-resident 1MB) instead of sincosf. Memory-bound target ~6 TB/s.
__global__ __launch_bounds__(256) void norm_rope(bf16* __restrict__ Qb,
                                                 bf16* __restrict__ Kb,
                                                 const float* __restrict__ gain,
                                                 const float2* __restrict__ tab) {
  const int lane = threadIdx.x & 63, wid = threadIdx.x >> 6;
  const int half = lane >> 5, l32 = lane & 31;
  const long rid = (long)blockIdx.x*8 + wid*2 + half;
  const long QR = (long)BSZ*NHEADS*SEQ;
  bf16* ptr; float g; int s;
  if (rid < QR) {
    ptr = Qb + rid*HD;
    s = (int)(rid & (SEQ-1));
    const int h = (int)((rid >> 11) & 15);
    g = gain[h] * 0.08838834764831845f;   // fold softmax scale 1/sqrt(128) into q
  } else {
    const long r2 = rid - QR;
    ptr = Kb + r2*HD;
    s = (int)(r2 & (SEQ-1));
    g = 1.0f;
  }
  // lane handles d = 2*l32, 2*l32+1 (first half) paired with d+64 (second half)
  const ushort2 xa = *(const ushort2*)(ptr + 2*l32);
  const ushort2 xb = *(const ushort2*)(ptr + 64 + 2*l32);
  const float x1a = bfu(xa.x), x1b = bfu(xa.y);
  const float x2a = bfu(xb.x), x2b = bfu(xb.y);
  float ss = x1a*x1a + x1b*x1b + x2a*x2a + x2b*x2b;
#pragma unroll
  for (int off = 1; off < 32; off <<= 1) ss += __shfl_xor(ss, off);  // within 32-group
  const float rn = rsqrtf(ss*(1.0f/128.0f) + 1.1920928955078125e-07f) * g;
  const float4 t4 = *(const float4*)(&tab[s*64 + 2*l32]);  // {c_a,s_a,c_b,s_b}
  const float q1a = x1a*rn, q1b = x1b*rn, q2a = x2a*rn, q2b = x2b*rn;
  ushort2 o1, o2;
  o1.x = fbu(q1a*t4.x + q2a*t4.y); o1.y = fbu(q1b*t4.z + q2b*t4.w);
  o2.x = fbu(q2a*t4.x - q1a*t4.y); o2.y = fbu(q2b*t4.z - q1b*t4.w);
  *(ushort2*)(ptr + 2*l32)      = o1;
  *(ushort2*)(ptr + 64 + 2*l32) = o2;
}

// -------- causal flash attention: S^T form, fixed-shift softmax, qt-paired --------
// T14 async-STAGE split; T5 setprio; T1 XCD swizzle.
__global__ __launch_bounds__(256, 2) void attn(
    const bf16* __restrict__ Qb, const bf16* __restrict__ Kb,
    const bf16* __restrict__ Vtg, bf16* __restrict__ Yb) {
  __shared__ short Kt[64*136]  __attribute__((aligned(16)));  // [key][k] pad->136
  __shared__ short Vt[128*72]  __attribute__((aligned(16)));  // [d][key] pad->72
  __shared__ short Pt[4*2304]  __attribute__((aligned(16)));  // per-wave, per-group [16 q][72]

  const int tid = threadIdx.x;
  const int lane = tid & 63, wid = tid >> 6;
  const int quad = lane >> 4, l15 = lane & 15;
  const int lin = blockIdx.y*8 + blockIdx.x;    // 512 blocks, %8==0
  const int swz = (lin & 7)*64 + (lin >> 3);    // bijective XCD chunking
  const int xb = swz & 7;                       // 0..7
  const int bh = swz >> 3;
  const int b = bh >> 4, h = bh & 15, kvh = h >> 2;

  const bf16* kbase = Kb  + (long)(b*NKVH + kvh)*SEQ*HD;
  const bf16* vbase = Vtg + (long)(b*NKVH + kvh)*HD*SEQ;   // [d][s]
  short* pw0 = Pt + wid*2304;
  short* pw1 = pw0 + 1152;
  const int krow = tid >> 4, kc = (tid & 15)*8;
  const int vrow = tid >> 3, vc = (tid & 7)*8;

#define LOADK(KT_) do {                                                        \
    kr0 = *(const uint4*)(kbase + (long)((KT_)*64 +  0 + krow)*HD + kc);       \
    kr1 = *(const uint4*)(kbase + (long)((KT_)*64 + 16 + krow)*HD + kc);       \
    kr2 = *(const uint4*)(kbase + (long)((KT_)*64 + 32 + krow)*HD + kc);       \
    kr3 = *(const uint4*)(kbase + (long)((KT_)*64 + 48 + krow)*HD + kc);       \
  } while (0)
#define LOADV(KT_) do {                                                        \
    vr0 = *(const uint4*)(vbase + (long)(  0 + vrow)*SEQ + (KT_)*64 + vc);     \
    vr1 = *(const uint4*)(vbase + (long)( 32 + vrow)*SEQ + (KT_)*64 + vc);     \
    vr2 = *(const uint4*)(vbase + (long)( 64 + vrow)*SEQ + (KT_)*64 + vc);     \
    vr3 = *(const uint4*)(vbase + (long)( 96 + vrow)*SEQ + (KT_)*64 + vc);     \
  } while (0)

  for (int phase = 0; phase < 2; phase++) {
    const int qt = phase ? xb : (15 - xb);      // heavy first
    const int q0 = qt*128 + wid*16 + l15;       // group 0 query
    const int q1 = q0 + 64;                     // group 1 query
    const bf16* qr0 = Qb + ((long)(b*NHEADS + h)*SEQ + q0)*HD + quad*8;
    s16x8 qa0[4], qa1[4];
#pragma unroll
    for (int st = 0; st < 4; st++) {
      qa0[st] = *(const s16x8*)(qr0 + st*32);
      qa1[st] = *(const s16x8*)(qr0 + 64*HD + st*32);
    }

    f32x4 o0[8] = {}, o1[8] = {};
    float li0 = 0.0f, li1 = 0.0f;
    const int ktiles = 2*qt + 2;

    uint4 kr0, kr1, kr2, kr3, vr0, vr1, vr2, vr3;
    LOADK(0); LOADV(0);                          // prologue issue (exposed once)

    for (int kt = 0; kt < ktiles; kt++) {
      __syncthreads();                           // all waves done reading prev tile
      // publish tile kt (compiler inserts the vmcnt wait before first ds_write)
      *(uint4*)&Kt[( 0 + krow)*136 + kc] = kr0;
      *(uint4*)&Kt[(16 + krow)*136 + kc] = kr1;
      *(uint4*)&Kt[(32 + krow)*136 + kc] = kr2;
      *(uint4*)&Kt[(48 + krow)*136 + kc] = kr3;
      *(uint4*)&Vt[(  0 + vrow)*72 + vc] = vr0;
      *(uint4*)&Vt[( 32 + vrow)*72 + vc] = vr1;
      *(uint4*)&Vt[( 64 + vrow)*72 + vc] = vr2;
      *(uint4*)&Vt[( 96 + vrow)*72 + vc] = vr3;
      __syncthreads();                           // tile kt visible
      if (kt + 1 < ktiles) { LOADK(kt+1); LOADV(kt+1); }  // T14: hide under compute

      // S^T = K Q^T for both groups; kf frags shared
      f32x4 s0[4] = {}, s1[4] = {};
#pragma unroll
      for (int nt = 0; nt < 4; nt++) {
        s16x8 kf[4];
#pragma unroll
        for (int st = 0; st < 4; st++)
          kf[st] = *(const s16x8*)&Kt[(nt*16 + l15)*136 + st*32 + quad*8];
        PRI1;
#pragma unroll
        for (int st = 0; st < 4; st++) {
          s0[nt] = __builtin_amdgcn_mfma_f32_16x16x32_bf16(kf[st], qa0[st], s0[nt], 0, 0, 0);
          s1[nt] = __builtin_amdgcn_mfma_f32_16x16x32_bf16(kf[st], qa1[st], s1[nt], 0, 0, 0);
        }
        PRI0;
      }

      // fixed-shift softmax: P = exp(s - 12); |s|<11.5 provably (rms-normed q,k)
      const bool d0 = (kt >= 2*qt);
      const bool d1 = (kt >  2*qt);
      const int tb = kt*64 + quad*4;
      union { bf16 h[16]; unsigned long long u[4]; } p0, p1;
      float rs0 = 0.0f, rs1 = 0.0f;
#pragma unroll
      for (int nt = 0; nt < 4; nt++) {
#pragma unroll
        for (int r = 0; r < 4; r++) {
          const int t = tb + nt*16 + r;
          float v0 = s0[nt][r], v1 = s1[nt][r];
          if (d0 && (t > q0)) v0 = -1e30f;
          if (d1 && (t > q1)) v1 = -1e30f;
          const float e0 = __expf(v0 - 12.0f);
          const float e1 = __expf(v1 - 12.0f);
          rs0 += e0; rs1 += e1;
          p0.h[nt*4+r] = __float2bfloat16(e0);
          p1.h[nt*4+r] = __float2bfloat16(e1);
        }
      }
      li0 += rs0; li1 += rs1;
#pragma unroll
      for (int nt = 0; nt < 4; nt++) {
        *(unsigned long long*)&pw0[l15*72 + nt*16 + quad*4] = p0.u[nt];
        *(unsigned long long*)&pw1[l15*72 + nt*16 + quad*4] = p1.u[nt];
      }

      // O^T += V^T P^T for both groups; vf frags shared
#pragma unroll
      for (int st = 0; st < 2; st++) {
        s16x8 pf0 = *(const s16x8*)&pw0[l15*72 + st*32 + quad*8];
        s16x8 pf1 = *(const s16x8*)&pw1[l15*72 + st*32 + quad*8];
        PRI1;
#pragma unroll
        for (int dt = 0; dt < 8; dt++) {
          s16x8 vf = *(const s16x8*)&Vt[(dt*16 + l15)*72 + st*32 + quad*8];
          o0[dt] = __builtin_amdgcn_mfma_f32_16x16x32_bf16(vf, pf0, o0[dt], 0, 0, 0);
          o1[dt] = __builtin_amdgcn_mfma_f32_16x16x32_bf16(vf, pf1, o1[dt], 0, 0, 0);
        }
        PRI0;
      }
    }

    // finalize li (once per phase), then transpose O^T -> O via wave-private Pt slice
    li0 += __shfl_xor(li0, 16); li0 += __shfl_xor(li0, 32);
    li1 += __shfl_xor(li1, 16); li1 += __shfl_xor(li1, 32);
    const float inv0 = 1.0f / li0, inv1 = 1.0f / li1;

    short* ep = pw0;
#pragma unroll
    for (int g = 0; g < 2; g++) {
      const float inv = g ? inv1 : inv0;
      const f32x4* o = g ? o1 : o0;
      const int qg = g ? q1 : q0;
#pragma unroll
      for (int dt = 0; dt < 8; dt++) {
        union { bf16 h[4]; unsigned long long u; } pk;
        pk.h[0] = __float2bfloat16(o[dt][0]*inv);
        pk.h[1] = __float2bfloat16(o[dt][1]*inv);
        pk.h[2] = __float2bfloat16(o[dt][2]*inv);
        pk.h[3] = __float2bfloat16(o[dt][3]*inv);
        *(unsigned long long*)&ep[l15*136 + dt*16 + quad*4] = pk.u;
      }
      bf16* yb = Yb + ((long)(b*SEQ + qg - l15))*DIM + h*HD;
#pragma unroll
      for (int p = 0; p < 4; p++) {
        const int c = quad + 4*p;
        uint4 yv = *(const uint4*)&ep[l15*136 + c*8];
        *(uint4*)&yb[(long)l15*DIM + c*8] = yv;
      }
    }
  }
#undef LOADK
#undef LOADV
}

extern "C" void kernel_launch(void* const* d_in, const int* in_sizes, int n_in,
                              void* d_out, int out_size, void* d_ws, size_t ws_size,
                              hipStream_t stream) {
  (void)in_sizes; (void)n_in; (void)out_size; (void)ws_size;
  const float* x   = (const float*)d_in[0];
  const float* Wq  = (const float*)d_in[1];
  const float* Wk  = (const float*)d_in[2];
  const float* Wv  = (const float*)d_in[3];
  const float* Wo  = (const float*)d_in[4];
  const float* qg  = (const float*)d_in[5];

  char* ws = (char*)d_ws;
  bf16* xbf  = (bf16*)(ws);                         // 32 MB
  bf16* Wqkv = (bf16*)(ws + 33554432);              // 12 MB
  bf16* Wob  = (bf16*)(ws + 46137344);              //  8 MB
  bf16* Qb   = (bf16*)(ws + 54525952);              // 32 MB
  bf16* Kb   = (bf16*)(ws + 88080384);              //  8 MB
  bf16* Vb   = (bf16*)(ws + 96468992);              //  8 MB (transposed [b,kvh,d,s])
  bf16* Yb   = (bf16*)(ws + 104857600);             // 32 MB
  // RoPE table aliases Yb (1MB): consumed by norm_rope BEFORE attn writes Yb
  float2* tab = (float2*)(ws + 104857600);

  cast_all<<<13824, 256, 0, stream>>>(x, Wq, Wk, Wv, Wo, xbf, Wqkv, Wob, tab);

  gemm8<1><<<dim3(NQKV/256, MROWS/256), 512, 0, stream>>>(
      xbf, Wqkv, nullptr, Qb, Kb, Vb, NQKV, DIM);

  norm_rope<<<20480, 256, 0, stream>>>(Qb, Kb, qg, tab);

  attn<<<dim3(8, BSZ*NHEADS), 256, 0, stream>>>(Qb, Kb, Vb, Yb);

  gemm8<0><<<dim3(DIM/256, MROWS/256), 512, 0, stream>>>(
      Yb, Wob, (float*)d_out, nullptr, nullptr, nullptr, DIM, DIM);
}